// Round 1
// 839.134 us; speedup vs baseline: 1.0228x; 1.0228x over previous
//
#include <hip/hip_runtime.h>
#include <hip/hip_bf16.h>

#define N_NODES 1000000
#define D_IN 128
#define NG 4096
#define GSD 128
#define NGROUP_MAX 35232               /* 8808 blocks * 4 waves >= 35218 worst case */
#define K5_BLOCKS 8808
#define CPAD 16                        /* one counter per 64B line to break atomic line-serialization */

typedef __attribute__((ext_vector_type(4))) float f32x4;
typedef __attribute__((ext_vector_type(8))) short bf16x8;
typedef __attribute__((ext_vector_type(4))) int i32x4;

__device__ __forceinline__ short f2bs(float f) {
    unsigned u = __float_as_uint(f);
    u += 0x7FFF + ((u >> 16) & 1);   // round-to-nearest-even
    return (short)(u >> 16);
}

// HW packed fp32->bf16 (RNE). dst[15:0]=bf16(lo), dst[31:16]=bf16(hi). One VALU inst.
__device__ __forceinline__ int cvt_pk_bf16(float lo, float hi) {
    int r;
    asm("v_cvt_pk_bf16_f32 %0, %1, %2" : "=v"(r) : "v"(lo), "v"(hi));
    return r;
}

__device__ __forceinline__ float sigmoid_fast(float x) {
    float e = __builtin_amdgcn_exp2f(-1.44269504089f * x);
    return __builtin_amdgcn_rcpf(1.0f + e);
}

// ---------------- weight transpose + bf16 convert (XOR-swizzled chunk layout) ----------------
// w1t slot n*128 + c*8 + j holds bf16(W1[k][n]) with k = ((c ^ (n&15))<<3)|j   (n<64, k<128)
// w2t slot n*64  + c*8 + j holds bf16(W2[k][n]) with k = ((c ^ (n&7 ))<<3)|j   (n<256, k<64)
__global__ void wconv_kernel(const float* __restrict__ W1, const float* __restrict__ W2,
                             short* __restrict__ w1t, short* __restrict__ w2t) {
    int idx = blockIdx.x * 256 + threadIdx.x;
    if (idx < 8192) {
        int n = idx >> 7, rem = idx & 127, c = rem >> 3, j = rem & 7;
        int k = ((c ^ (n & 15)) << 3) | j;
        w1t[idx] = f2bs(W1[k * 64 + n]);
    } else {
        int s = idx - 8192;
        int n = s >> 6, rem = s & 63, c = rem >> 3, j = rem & 7;
        int k = ((c ^ (n & 7)) << 3) | j;
        w2t[s] = f2bs(W2[k * 256 + n]);
    }
}

// ---------------- histogram ----------------
__global__ void hist_kernel(const int* __restrict__ gidx, int* __restrict__ cnt) {
    __shared__ int h[NG];
    int t = threadIdx.x;
    for (int i = t; i < NG; i += 256) h[i] = 0;
    __syncthreads();
    for (int i = blockIdx.x * 256 + t; i < N_NODES; i += gridDim.x * 256)
        atomicAdd(&h[gidx[i]], 1);
    __syncthreads();
    for (int i = t; i < NG; i += 256) {
        int v = h[i];
        if (v) atomicAdd(&cnt[i * CPAD], v);
    }
}

// ---------------- scan (padded offsets) + encoded group-id fill + group count ----------------
__global__ __launch_bounds__(1024) void scan_kernel(const int* __restrict__ cnt,
                                                    int* __restrict__ poff,
                                                    int* __restrict__ ggid,
                                                    int* __restrict__ meta) {
    __shared__ int sc[1024];
    int t = threadIdx.x;
    int cc[4], c[4];
    int s = 0;
#pragma unroll
    for (int i = 0; i < 4; ++i) {
        cc[i] = cnt[(t * 4 + i) * CPAD];
        c[i] = (cc[i] + 31) & ~31;   // ceil to multiple of 32
        s += c[i];
    }
    sc[t] = s;
    __syncthreads();
    for (int off = 1; off < 1024; off <<= 1) {
        int v = (t >= off) ? sc[t - off] : 0;
        __syncthreads();
        sc[t] += v;
        __syncthreads();
    }
    if (t == 1023) meta[0] = sc[1023] >> 5;   // total #32-row groups
    int base = sc[t] - s;   // exclusive prefix (node units, multiple of 32)
#pragma unroll
    for (int i = 0; i < 4; ++i) {
        int g = t * 4 + i;
        poff[g] = base;
        int ngp = c[i] >> 5;
        int gb = base >> 5;
        for (int k = 0; k < ngp; ++k) {
            int rem = cc[i] - k * 32;
            int rows = rem > 32 ? 32 : rem;
            ggid[gb + k] = (g << 6) | (rows - 1);
        }
        base += c[i];
    }
}

// ---------------- scatter node ids into padded graph-sorted order ----------------
__global__ void scatter_kernel(const int* __restrict__ gidx, const int* __restrict__ poff,
                               int* __restrict__ cur, int* __restrict__ order) {
    int i = blockIdx.x * 256 + threadIdx.x;
    if (i >= N_NODES) return;
    int g = gidx[i];
    int p = atomicAdd(&cur[g * CPAD], 1);
    order[poff[g] + p] = i;
}

// ---------------- main fused kernel ----------------
// No weight staging: W1T/W2T fragments are read directly from global (48 KB, L2-resident;
// each 16-lane read group covers a full 64B line).  LDS = per-wave H1 only (4 x 4 KB).
__global__ __launch_bounds__(256, 4) void main_kernel(
        const float* __restrict__ X, const short* __restrict__ w1t,
        const short* __restrict__ w2t, const float* __restrict__ b1,
        const float* __restrict__ b2, const int* __restrict__ order,
        const int* __restrict__ ggid, const int* __restrict__ meta,
        float* __restrict__ gs) {
    __shared__ __align__(16) short lds[8192];   // 4 waves * 32x64 bf16 H1 (swizzled)
    const int tid = threadIdx.x;
    const int wid = tid >> 6;
    const int w = (blockIdx.x << 2) + wid;   // global 32-row group id
    const int lane = tid & 63;
    const int l15 = lane & 15;
    const int q = lane >> 4;
    const int ngroups = meta[0];
    const bool active = (w < ngroups);
    const int h1b = wid * 2048;

    int g = 0;
    unsigned rowmask = 0;

    if (active) {
        int enc = ggid[w];
        g = enc >> 6;
        int rows = (enc & 63) + 1;
        rowmask = (rows >= 32) ? 0xFFFFFFFFu : ((1u << rows) - 1u);
        bool v0 = l15 < rows;
        bool v1 = (16 + l15) < rows;
        int nd0r = order[w * 32 + l15];
        int nd1r = order[w * 32 + 16 + l15];
        const float* xp0 = X + (long long)(v0 ? nd0r : 0) * D_IN;
        const float* xp1 = X + (long long)(v1 ? nd1r : 0) * D_IN;

        f32x4 acc1[2][4];
#pragma unroll
        for (int mt = 0; mt < 2; ++mt)
#pragma unroll
            for (int nt = 0; nt < 4; ++nt) acc1[mt][nt] = (f32x4){0.f, 0.f, 0.f, 0.f};

        const f32x4 z = {0.f, 0.f, 0.f, 0.f};
#pragma unroll
        for (int kk = 0; kk < 4; ++kk) {
            int koff = kk * 32 + q * 8;
            f32x4 x00 = v0 ? *(const f32x4*)(xp0 + koff) : z;
            f32x4 x01 = v0 ? *(const f32x4*)(xp0 + koff + 4) : z;
            f32x4 x10 = v1 ? *(const f32x4*)(xp1 + koff) : z;
            f32x4 x11 = v1 ? *(const f32x4*)(xp1 + koff + 4) : z;
            union { bf16x8 v; int i[4]; } ua0, ua1;
            ua0.i[0] = cvt_pk_bf16(x00[0], x00[1]);
            ua0.i[1] = cvt_pk_bf16(x00[2], x00[3]);
            ua0.i[2] = cvt_pk_bf16(x01[0], x01[1]);
            ua0.i[3] = cvt_pk_bf16(x01[2], x01[3]);
            ua1.i[0] = cvt_pk_bf16(x10[0], x10[1]);
            ua1.i[1] = cvt_pk_bf16(x10[2], x10[3]);
            ua1.i[2] = cvt_pk_bf16(x11[0], x11[1]);
            ua1.i[3] = cvt_pk_bf16(x11[2], x11[3]);
            int ch = kk * 4 + q;
#pragma unroll
            for (int nt = 0; nt < 4; ++nt) {
                bf16x8 b = *(const bf16x8*)&w1t[(nt * 16 + l15) * 128 + ((ch ^ l15) << 3)];
                acc1[0][nt] = __builtin_amdgcn_mfma_f32_16x16x32_bf16(ua0.v, b, acc1[0][nt], 0, 0, 0);
                acc1[1][nt] = __builtin_amdgcn_mfma_f32_16x16x32_bf16(ua1.v, b, acc1[1][nt], 0, 0, 0);
            }
        }

        // epilogue 1: +b1, relu, bf16 -> H1 (swizzled A-operand layout, per-wave region)
#pragma unroll
        for (int nt = 0; nt < 4; ++nt) {
            float bb = b1[nt * 16 + l15];
            int c = nt * 2 + (l15 >> 3);
            int j7 = l15 & 7;
#pragma unroll
            for (int mt = 0; mt < 2; ++mt)
#pragma unroll
                for (int r = 0; r < 4; ++r) {
                    int m = mt * 16 + q * 4 + r;
                    float h = fmaxf(acc1[mt][nt][r] + bb, 0.f);
                    lds[h1b + m * 64 + ((c ^ (m & 7)) << 3) + j7] = (short)cvt_pk_bf16(h, h);
                }
        }
    }

    __syncthreads();   // H1 cross-lane visibility (all waves reach this)

    if (active) {
        // hoist A fragments once: rows 0-15 and 16-31, K slices 0/1
        bf16x8 A0[2], A1[2];
#pragma unroll
        for (int ks = 0; ks < 2; ++ks) {
            int ch = ((ks * 4 + q) ^ (l15 & 7)) << 3;
            A0[ks] = *(const bf16x8*)&lds[h1b + l15 * 64 + ch];
            A1[ks] = *(const bf16x8*)&lds[h1b + (16 + l15) * 64 + ch];
        }
#pragma unroll
        for (int nt = 0; nt < 8; ++nt) {
            f32x4 aG0 = (f32x4){0.f, 0.f, 0.f, 0.f}, aG1 = aG0, aV0 = aG0, aV1 = aG0;
#pragma unroll
            for (int ks = 0; ks < 2; ++ks) {
                int ch = ((ks * 4 + q) ^ (l15 & 7)) << 3;
                bf16x8 bG = *(const bf16x8*)&w2t[(nt * 16 + l15) * 64 + ch];
                bf16x8 bV = *(const bf16x8*)&w2t[((nt + 8) * 16 + l15) * 64 + ch];
                aG0 = __builtin_amdgcn_mfma_f32_16x16x32_bf16(A0[ks], bG, aG0, 0, 0, 0);
                aG1 = __builtin_amdgcn_mfma_f32_16x16x32_bf16(A1[ks], bG, aG1, 0, 0, 0);
                aV0 = __builtin_amdgcn_mfma_f32_16x16x32_bf16(A0[ks], bV, aV0, 0, 0, 0);
                aV1 = __builtin_amdgcn_mfma_f32_16x16x32_bf16(A1[ks], bV, aV1, 0, 0, 0);
            }
            float bg = b2[nt * 16 + l15];
            float bv = b2[128 + nt * 16 + l15];
            float s = 0.f;
#pragma unroll
            for (int mt = 0; mt < 2; ++mt) {
                f32x4 aG = mt ? aG1 : aG0;
                f32x4 aV = mt ? aV1 : aV0;
#pragma unroll
                for (int r = 0; r < 4; ++r) {
                    int row = mt * 16 + q * 4 + r;
                    float gate = sigmoid_fast(aG[r] + bg);
                    float gv = gate * (aV[r] + bv);
                    s += ((rowmask >> row) & 1u) ? gv : 0.f;
                }
            }
            s += __shfl_xor(s, 16);
            s += __shfl_xor(s, 32);
            if (lane < 16) unsafeAtomicAdd(&gs[(long long)g * GSD + nt * 16 + l15], s);
        }
    }
}

// ---------------- MLP2: [4096,128] -> relu(@W3+b3) -> @W4+b4 -> [4096,16] ----------------
__global__ void mlp2_kernel(const float* __restrict__ gs, const float* __restrict__ W3,
                            const float* __restrict__ b3, const float* __restrict__ W4,
                            const float* __restrict__ b4, float* __restrict__ out) {
    __shared__ __align__(16) float sgs[8 * 128];
    __shared__ float sh3[8 * 32];
    int t = threadIdx.x;
    int g0 = blockIdx.x * 8;
    *(f32x4*)&sgs[t * 4] = *(const f32x4*)(gs + (long long)g0 * 128 + t * 4);
    __syncthreads();
    {
        int li = t >> 5, j = t & 31;
        float acc = b3[j];
#pragma unroll 8
        for (int k = 0; k < 128; ++k) acc += sgs[li * 128 + k] * W3[k * 32 + j];
        sh3[li * 32 + j] = fmaxf(acc, 0.f);
    }
    __syncthreads();
    if (t < 128) {
        int li = t >> 4, o = t & 15;
        float acc = b4[o];
#pragma unroll
        for (int j = 0; j < 32; ++j) acc += sh3[li * 32 + j] * W4[j * 16 + o];
        out[(g0 + li) * 16 + o] = acc;
    }
}

extern "C" void kernel_launch(void* const* d_in, const int* in_sizes, int n_in,
                              void* d_out, int out_size, void* d_ws, size_t ws_size,
                              hipStream_t stream) {
    (void)in_sizes; (void)n_in; (void)out_size; (void)ws_size;
    const float* X  = (const float*)d_in[0];
    const int* gidx = (const int*)d_in[1];
    const float* W1 = (const float*)d_in[2];
    const float* b1 = (const float*)d_in[3];
    const float* W2 = (const float*)d_in[4];
    const float* b2 = (const float*)d_in[5];
    const float* W3 = (const float*)d_in[6];
    const float* b3 = (const float*)d_in[7];
    const float* W4 = (const float*)d_in[8];
    const float* b4 = (const float*)d_in[9];
    float* out = (float*)d_out;

    char* ws   = (char*)d_ws;
    float* gs  = (float*)(ws + 0);          // 2,097,152 B
    int* cnt   = (int*)(ws + 2097152);      // 262,144 B (padded x16)
    int* cur   = (int*)(ws + 2359296);      // 262,144 B (padded x16)
    int* poff  = (int*)(ws + 2621440);      // 16,384 B
    int* meta  = (int*)(ws + 2637824);      // 64 B
    short* w1t = (short*)(ws + 2637888);    // 16,384 B
    short* w2t = (short*)(ws + 2654272);    // 32,768 B
    int* ggid  = (int*)(ws + 2687040);      // 140,928 B
    int* order = (int*)(ws + 2827968);      // 4,507,904 B -> end 7,335,872 B

    // zero gs + cnt + cur in one fill (poff/meta/ggid/order are fully written before use)
    hipMemsetAsync(ws, 0, 2621440, stream);

    wconv_kernel<<<96, 256, 0, stream>>>(W1, W2, w1t, w2t);
    hist_kernel<<<512, 256, 0, stream>>>(gidx, cnt);
    scan_kernel<<<1, 1024, 0, stream>>>(cnt, poff, ggid, meta);
    scatter_kernel<<<(N_NODES + 255) / 256, 256, 0, stream>>>(gidx, poff, cur, order);
    main_kernel<<<K5_BLOCKS, 256, 0, stream>>>(X, w1t, w2t, b1, b2, order, ggid, meta, gs);
    mlp2_kernel<<<512, 256, 0, stream>>>(gs, W3, b3, W4, b4, out);
}

// Round 2
// 814.015 us; speedup vs baseline: 1.0544x; 1.0309x over previous
//
#include <hip/hip_runtime.h>
#include <hip/hip_bf16.h>

#define N_NODES 1000000
#define D_IN 128
#define NG 4096
#define GSD 128
#define NGROUP_MAX 35232               /* 8808 blocks * 4 waves >= 35218 worst case */
#define K5_BLOCKS 8808
#define CPAD 16                        /* one counter per 64B line for contended fetch-adds */
#define HIST_BLOCKS 64

typedef __attribute__((ext_vector_type(4))) float f32x4;
typedef __attribute__((ext_vector_type(8))) short bf16x8;
typedef __attribute__((ext_vector_type(4))) int i32x4;

__device__ __forceinline__ short f2bs(float f) {
    unsigned u = __float_as_uint(f);
    u += 0x7FFF + ((u >> 16) & 1);   // round-to-nearest-even
    return (short)(u >> 16);
}

// HW packed fp32->bf16 (RNE). dst[15:0]=bf16(lo), dst[31:16]=bf16(hi). One VALU inst.
__device__ __forceinline__ int cvt_pk_bf16(float lo, float hi) {
    int r;
    asm("v_cvt_pk_bf16_f32 %0, %1, %2" : "=v"(r) : "v"(lo), "v"(hi));
    return r;
}

__device__ __forceinline__ float sigmoid_fast(float x) {
    float e = __builtin_amdgcn_exp2f(-1.44269504089f * x);
    return __builtin_amdgcn_rcpf(1.0f + e);
}

// ---------------- weight transpose + bf16 convert (XOR-swizzled chunk layout) ----------------
// w1t slot n*128 + c*8 + j holds bf16(W1[k][n]) with k = ((c ^ (n&15))<<3)|j   (n<64, k<128)
// w2t slot n*64  + c*8 + j holds bf16(W2[k][n]) with k = ((c ^ (n&7 ))<<3)|j   (n<256, k<64)
__global__ void wconv_kernel(const float* __restrict__ W1, const float* __restrict__ W2,
                             short* __restrict__ w1t, short* __restrict__ w2t) {
    int idx = blockIdx.x * 256 + threadIdx.x;
    if (idx < 8192) {
        int n = idx >> 7, rem = idx & 127, c = rem >> 3, j = rem & 7;
        int k = ((c ^ (n & 15)) << 3) | j;
        w1t[idx] = f2bs(W1[k * 64 + n]);
    } else {
        int s = idx - 8192;
        int n = s >> 6, rem = s & 63, c = rem >> 3, j = rem & 7;
        int k = ((c ^ (n & 7)) << 3) | j;
        w2t[s] = f2bs(W2[k * 256 + n]);
    }
}

// ---------------- histogram: per-block partials, no global atomics ----------------
__global__ __launch_bounds__(1024) void hist_kernel(const int* __restrict__ gidx,
                                                    int* __restrict__ part) {
    __shared__ int h[NG];
    int t = threadIdx.x;
    for (int i = t; i < NG; i += 1024) h[i] = 0;
    __syncthreads();
    const i32x4* g4 = (const i32x4*)gidx;
    for (int i = blockIdx.x * 1024 + t; i < N_NODES / 4; i += HIST_BLOCKS * 1024) {
        i32x4 v = g4[i];
        atomicAdd(&h[v[0]], 1);
        atomicAdd(&h[v[1]], 1);
        atomicAdd(&h[v[2]], 1);
        atomicAdd(&h[v[3]], 1);
    }
    __syncthreads();
    for (int i = t; i < NG; i += 1024) part[blockIdx.x * NG + i] = h[i];
}

// ---------------- scan: reduce partials + padded offsets + encoded group ids + cur zero ----------------
__global__ __launch_bounds__(1024) void scan_kernel(const int* __restrict__ part,
                                                    int* __restrict__ poff,
                                                    int* __restrict__ ggid,
                                                    int* __restrict__ meta,
                                                    int* __restrict__ cur) {
    __shared__ int sc[1024];
    int t = threadIdx.x;
    // 64-way reduction of per-block partials (coalesced int4 reads)
    i32x4 a4 = (i32x4){0, 0, 0, 0};
#pragma unroll 8
    for (int b = 0; b < HIST_BLOCKS; ++b)
        a4 += *(const i32x4*)&part[b * NG + t * 4];
    int cc[4], c[4];
    int s = 0;
#pragma unroll
    for (int i = 0; i < 4; ++i) {
        cc[i] = a4[i];
        c[i] = (cc[i] + 31) & ~31;   // ceil to multiple of 32
        s += c[i];
    }
    sc[t] = s;
    __syncthreads();
    for (int off = 1; off < 1024; off <<= 1) {
        int v = (t >= off) ? sc[t - off] : 0;
        __syncthreads();
        sc[t] += v;
        __syncthreads();
    }
    if (t == 1023) meta[0] = sc[1023] >> 5;   // total #32-row groups
    int base = sc[t] - s;   // exclusive prefix (node units, multiple of 32)
#pragma unroll
    for (int i = 0; i < 4; ++i) {
        int g = t * 4 + i;
        poff[g] = base;
        cur[g * CPAD] = 0;
        int ngp = c[i] >> 5;
        int gb = base >> 5;
        for (int k = 0; k < ngp; ++k) {
            int rem = cc[i] - k * 32;
            int rows = rem > 32 ? 32 : rem;
            ggid[gb + k] = (g << 6) | (rows - 1);
        }
        base += c[i];
    }
}

// ---------------- scatter node ids into padded graph-sorted order (+ gs zero) ----------------
__global__ void scatter_kernel(const int* __restrict__ gidx, const int* __restrict__ poff,
                               int* __restrict__ cur, int* __restrict__ order,
                               float* __restrict__ gs) {
    int i = blockIdx.x * 256 + threadIdx.x;
    if (i < (NG * GSD) / 4)
        *(f32x4*)&gs[i * 4] = (f32x4){0.f, 0.f, 0.f, 0.f};
    if (i >= N_NODES) return;
    int g = gidx[i];
    int p = atomicAdd(&cur[g * CPAD], 1);
    order[poff[g] + p] = i;
}

// ---------------- main fused kernel ----------------
// No weight staging: W1T/W2T fragments are read directly from global (48 KB, L2-resident;
// each 16-lane read group covers a full 64B line).  LDS = per-wave H1 only (4 x 4 KB).
__global__ __launch_bounds__(256, 4) void main_kernel(
        const float* __restrict__ X, const short* __restrict__ w1t,
        const short* __restrict__ w2t, const float* __restrict__ b1,
        const float* __restrict__ b2, const int* __restrict__ order,
        const int* __restrict__ ggid, const int* __restrict__ meta,
        float* __restrict__ gs) {
    __shared__ __align__(16) short lds[8192];   // 4 waves * 32x64 bf16 H1 (swizzled)
    const int tid = threadIdx.x;
    const int wid = tid >> 6;
    const int w = (blockIdx.x << 2) + wid;   // global 32-row group id
    const int lane = tid & 63;
    const int l15 = lane & 15;
    const int q = lane >> 4;
    const int ngroups = meta[0];
    const bool active = (w < ngroups);
    const int h1b = wid * 2048;

    int g = 0;
    unsigned rowmask = 0;

    if (active) {
        int enc = ggid[w];
        g = enc >> 6;
        int rows = (enc & 63) + 1;
        rowmask = (rows >= 32) ? 0xFFFFFFFFu : ((1u << rows) - 1u);
        bool v0 = l15 < rows;
        bool v1 = (16 + l15) < rows;
        int nd0r = order[w * 32 + l15];
        int nd1r = order[w * 32 + 16 + l15];
        const float* xp0 = X + (long long)(v0 ? nd0r : 0) * D_IN;
        const float* xp1 = X + (long long)(v1 ? nd1r : 0) * D_IN;

        f32x4 acc1[2][4];
#pragma unroll
        for (int mt = 0; mt < 2; ++mt)
#pragma unroll
            for (int nt = 0; nt < 4; ++nt) acc1[mt][nt] = (f32x4){0.f, 0.f, 0.f, 0.f};

        const f32x4 z = {0.f, 0.f, 0.f, 0.f};
#pragma unroll
        for (int kk = 0; kk < 4; ++kk) {
            int koff = kk * 32 + q * 8;
            f32x4 x00 = v0 ? *(const f32x4*)(xp0 + koff) : z;
            f32x4 x01 = v0 ? *(const f32x4*)(xp0 + koff + 4) : z;
            f32x4 x10 = v1 ? *(const f32x4*)(xp1 + koff) : z;
            f32x4 x11 = v1 ? *(const f32x4*)(xp1 + koff + 4) : z;
            union { bf16x8 v; int i[4]; } ua0, ua1;
            ua0.i[0] = cvt_pk_bf16(x00[0], x00[1]);
            ua0.i[1] = cvt_pk_bf16(x00[2], x00[3]);
            ua0.i[2] = cvt_pk_bf16(x01[0], x01[1]);
            ua0.i[3] = cvt_pk_bf16(x01[2], x01[3]);
            ua1.i[0] = cvt_pk_bf16(x10[0], x10[1]);
            ua1.i[1] = cvt_pk_bf16(x10[2], x10[3]);
            ua1.i[2] = cvt_pk_bf16(x11[0], x11[1]);
            ua1.i[3] = cvt_pk_bf16(x11[2], x11[3]);
            int ch = kk * 4 + q;
#pragma unroll
            for (int nt = 0; nt < 4; ++nt) {
                bf16x8 b = *(const bf16x8*)&w1t[(nt * 16 + l15) * 128 + ((ch ^ l15) << 3)];
                acc1[0][nt] = __builtin_amdgcn_mfma_f32_16x16x32_bf16(ua0.v, b, acc1[0][nt], 0, 0, 0);
                acc1[1][nt] = __builtin_amdgcn_mfma_f32_16x16x32_bf16(ua1.v, b, acc1[1][nt], 0, 0, 0);
            }
        }

        // epilogue 1: +b1, relu, bf16 -> H1 (swizzled A-operand layout, per-wave region)
#pragma unroll
        for (int nt = 0; nt < 4; ++nt) {
            float bb = b1[nt * 16 + l15];
            int c = nt * 2 + (l15 >> 3);
            int j7 = l15 & 7;
#pragma unroll
            for (int mt = 0; mt < 2; ++mt)
#pragma unroll
                for (int r = 0; r < 4; ++r) {
                    int m = mt * 16 + q * 4 + r;
                    float h = fmaxf(acc1[mt][nt][r] + bb, 0.f);
                    lds[h1b + m * 64 + ((c ^ (m & 7)) << 3) + j7] = (short)cvt_pk_bf16(h, h);
                }
        }
    }

    __syncthreads();   // H1 cross-lane visibility (all waves reach this)

    if (active) {
        // hoist A fragments once: rows 0-15 and 16-31, K slices 0/1
        bf16x8 A0[2], A1[2];
#pragma unroll
        for (int ks = 0; ks < 2; ++ks) {
            int ch = ((ks * 4 + q) ^ (l15 & 7)) << 3;
            A0[ks] = *(const bf16x8*)&lds[h1b + l15 * 64 + ch];
            A1[ks] = *(const bf16x8*)&lds[h1b + (16 + l15) * 64 + ch];
        }
#pragma unroll
        for (int nt = 0; nt < 8; ++nt) {
            f32x4 aG0 = (f32x4){0.f, 0.f, 0.f, 0.f}, aG1 = aG0, aV0 = aG0, aV1 = aG0;
#pragma unroll
            for (int ks = 0; ks < 2; ++ks) {
                int ch = ((ks * 4 + q) ^ (l15 & 7)) << 3;
                bf16x8 bG = *(const bf16x8*)&w2t[(nt * 16 + l15) * 64 + ch];
                bf16x8 bV = *(const bf16x8*)&w2t[((nt + 8) * 16 + l15) * 64 + ch];
                aG0 = __builtin_amdgcn_mfma_f32_16x16x32_bf16(A0[ks], bG, aG0, 0, 0, 0);
                aG1 = __builtin_amdgcn_mfma_f32_16x16x32_bf16(A1[ks], bG, aG1, 0, 0, 0);
                aV0 = __builtin_amdgcn_mfma_f32_16x16x32_bf16(A0[ks], bV, aV0, 0, 0, 0);
                aV1 = __builtin_amdgcn_mfma_f32_16x16x32_bf16(A1[ks], bV, aV1, 0, 0, 0);
            }
            float bg = b2[nt * 16 + l15];
            float bv = b2[128 + nt * 16 + l15];
            float s = 0.f;
#pragma unroll
            for (int mt = 0; mt < 2; ++mt) {
                f32x4 aG = mt ? aG1 : aG0;
                f32x4 aV = mt ? aV1 : aV0;
#pragma unroll
                for (int r = 0; r < 4; ++r) {
                    int row = mt * 16 + q * 4 + r;
                    float gate = sigmoid_fast(aG[r] + bg);
                    float gv = gate * (aV[r] + bv);
                    s += ((rowmask >> row) & 1u) ? gv : 0.f;
                }
            }
            s += __shfl_xor(s, 16);
            s += __shfl_xor(s, 32);
            if (lane < 16) unsafeAtomicAdd(&gs[(long long)g * GSD + nt * 16 + l15], s);
        }
    }
}

// ---------------- MLP2: [4096,128] -> relu(@W3+b3) -> @W4+b4 -> [4096,16] ----------------
__global__ void mlp2_kernel(const float* __restrict__ gs, const float* __restrict__ W3,
                            const float* __restrict__ b3, const float* __restrict__ W4,
                            const float* __restrict__ b4, float* __restrict__ out) {
    __shared__ __align__(16) float sgs[8 * 128];
    __shared__ float sh3[8 * 32];
    int t = threadIdx.x;
    int g0 = blockIdx.x * 8;
    *(f32x4*)&sgs[t * 4] = *(const f32x4*)(gs + (long long)g0 * 128 + t * 4);
    __syncthreads();
    {
        int li = t >> 5, j = t & 31;
        float acc = b3[j];
#pragma unroll 8
        for (int k = 0; k < 128; ++k) acc += sgs[li * 128 + k] * W3[k * 32 + j];
        sh3[li * 32 + j] = fmaxf(acc, 0.f);
    }
    __syncthreads();
    if (t < 128) {
        int li = t >> 4, o = t & 15;
        float acc = b4[o];
#pragma unroll
        for (int j = 0; j < 32; ++j) acc += sh3[li * 32 + j] * W4[j * 16 + o];
        out[(g0 + li) * 16 + o] = acc;
    }
}

extern "C" void kernel_launch(void* const* d_in, const int* in_sizes, int n_in,
                              void* d_out, int out_size, void* d_ws, size_t ws_size,
                              hipStream_t stream) {
    (void)in_sizes; (void)n_in; (void)out_size; (void)ws_size;
    const float* X  = (const float*)d_in[0];
    const int* gidx = (const int*)d_in[1];
    const float* W1 = (const float*)d_in[2];
    const float* b1 = (const float*)d_in[3];
    const float* W2 = (const float*)d_in[4];
    const float* b2 = (const float*)d_in[5];
    const float* W3 = (const float*)d_in[6];
    const float* b3 = (const float*)d_in[7];
    const float* W4 = (const float*)d_in[8];
    const float* b4 = (const float*)d_in[9];
    float* out = (float*)d_out;

    char* ws   = (char*)d_ws;
    float* gs  = (float*)(ws + 0);          // 2,097,152 B   (zeroed in scatter prologue)
    int* cur   = (int*)(ws + 2097152);      // 262,144 B     (zeroed in scan)
    int* poff  = (int*)(ws + 2359296);      // 16,384 B      (fully written in scan)
    int* meta  = (int*)(ws + 2375680);      // 64 B          (written in scan)
    short* w1t = (short*)(ws + 2375744);    // 16,384 B      (fully written in wconv)
    short* w2t = (short*)(ws + 2392128);    // 32,768 B      (fully written in wconv)
    int* ggid  = (int*)(ws + 2424896);      // 140,928 B     (written in scan for w<ngroups)
    int* part  = (int*)(ws + 2565824);      // 1,048,576 B   (fully written in hist)
    int* order = (int*)(ws + 3614400);      // 4,507,904 B -> end 8,122,304 B

    wconv_kernel<<<96, 256, 0, stream>>>(W1, W2, w1t, w2t);
    hist_kernel<<<HIST_BLOCKS, 1024, 0, stream>>>(gidx, part);
    scan_kernel<<<1, 1024, 0, stream>>>(part, poff, ggid, meta, cur);
    scatter_kernel<<<(N_NODES + 255) / 256, 256, 0, stream>>>(gidx, poff, cur, order, gs);
    main_kernel<<<K5_BLOCKS, 256, 0, stream>>>(X, w1t, w2t, b1, b2, order, ggid, meta, gs);
    mlp2_kernel<<<512, 256, 0, stream>>>(gs, W3, b3, W4, b4, out);
}